// Round 4
// baseline (1981.249 us; speedup 1.0000x reference)
//
#include <hip/hip_runtime.h>
#include <hip/hip_bf16.h>
#include <math.h>

// Problem constants
#define B_    16
#define D_    256
#define T_    2048
#define K_    1024
#define BT_   (B_ * T_)            // 32768 rows
#define BDT_  (B_ * D_ * T_)       // 8388608 elements
#define MUSIC_W 0.1f
#define EPS_COS 1e-8f
#define MARGIN_TAU 6e-4f           // > 2*e_mfma(7e-5) + 2*delta_np(6e-5), 2x headroom

typedef _Float16 half8v __attribute__((ext_vector_type(8)));
typedef float f32x4 __attribute__((ext_vector_type(4)));

// ---------------------------------------------------------------------------
// numpy pairwise sum-of-squares (exact replication for n=128 / n=256).
// ---------------------------------------------------------------------------
__device__ __forceinline__ float pw128_sq(const float* a, int stride) {
    float r[8];
    #pragma unroll
    for (int j = 0; j < 8; ++j) { float v = a[j * stride]; r[j] = __fmul_rn(v, v); }
    for (int i = 8; i < 128; i += 8) {
        #pragma unroll
        for (int j = 0; j < 8; ++j) {
            float v = a[(i + j) * stride];
            r[j] = __fadd_rn(r[j], __fmul_rn(v, v));
        }
    }
    return __fadd_rn(__fadd_rn(__fadd_rn(r[0], r[1]), __fadd_rn(r[2], r[3])),
                     __fadd_rn(__fadd_rn(r[4], r[5]), __fadd_rn(r[6], r[7])));
}
__device__ __forceinline__ float pw256_sq(const float* a, int stride) {
    return __fadd_rn(pw128_sq(a, stride), pw128_sq(a + 128 * stride, stride));
}

// ---------------------------------------------------------------------------
// Kernel 1: prep — ct[d][k] f32 transpose (fallback path), cph packed fp16
// codebook [d/8][k][8] (MFMA B-fragments), zero counts / sums / fb_count.
// ---------------------------------------------------------------------------
__global__ __launch_bounds__(256) void prep_trans(const float* __restrict__ cb,
                                                  float* __restrict__ ct,
                                                  _Float16* __restrict__ cph,
                                                  float* __restrict__ counts,
                                                  double* __restrict__ sums,
                                                  int* __restrict__ fb_count) {
    int k = blockIdx.x;        // 0..1023
    int d = threadIdx.x;       // 0..255
    float v = cb[k * D_ + d];
    ct[d * K_ + k] = v;
    cph[((d >> 3) * K_ + k) * 8 + (d & 7)] = (_Float16)v;
    if (d == 0) counts[k] = 0.0f;
    if (k == 0 && d < 2) sums[d] = 0.0;
    if (k == 0 && d == 0) *fb_count = 0;
}

// ---------------------------------------------------------------------------
// Kernel 2: cc[k] = np-pairwise-f32 sum of codebook row squares.
// ---------------------------------------------------------------------------
__global__ __launch_bounds__(256) void prep_cc(const float* __restrict__ cb,
                                               float* __restrict__ c2) {
    int k = blockIdx.x * 256 + threadIdx.x;
    if (k < K_) c2[k] = pw256_sq(cb + (size_t)k * D_, 1);
}

// ---------------------------------------------------------------------------
// Kernel 3: argmin via fp16 MFMA. Block = 256 thr (4 waves), 32 rows.
// Wave w covers codes [w*256, w*256+256). Per wave: A-frags (fp16 x-tile)
// cached in regs; 16 n-tiles x 8 k-steps x 2 m-tiles MFMA; top-2 tracking;
// cross-lane + cross-wave merge; margin >= TAU -> commit, else flag row.
// A layout: lane holds A[m=lane&15][k=(lane>>4)*8+j]; B: B[k][n=lane&15];
// D: row=(lane>>4)*4+i, col=lane&15 (m89-verified convention).
// ---------------------------------------------------------------------------
#define XSTR 260

__global__ __launch_bounds__(256) void argmin_kernel(const float* __restrict__ x,
                                                     const _Float16* __restrict__ cph,
                                                     const float* __restrict__ c2,
                                                     int* __restrict__ codes,
                                                     float* __restrict__ codes_f,
                                                     int* __restrict__ fb_count,
                                                     int* __restrict__ fb_rows) {
    __shared__ __align__(16) float xs[32 * XSTR];
    __shared__ float wbest[4][32];
    __shared__ float wsec[4][32];
    __shared__ int   wk[4][32];

    int blk = blockIdx.x;            // 0..1023
    int row0 = blk * 32;
    int b = row0 >> 11;
    int t0 = row0 & 2047;
    const float* xb = x + (size_t)b * (D_ * T_);

    int tid = threadIdx.x;
    int li = tid & 31;
    int dhi = tid >> 5;
    #pragma unroll 4
    for (int p = 0; p < 32; ++p) {
        int d = p * 8 + dhi;
        xs[li * XSTR + d] = xb[d * T_ + t0 + li];
    }
    __syncthreads();

    int wave = tid >> 6;
    int lane = tid & 63;
    int lmod = lane & 15;
    int lgrp = lane >> 4;            // 0..3

    // ---- build fp16 A fragments: afrag[mt][kb], dims = kb*32 + lgrp*8 + j
    half8v afrag[2][8];
    #pragma unroll
    for (int mt = 0; mt < 2; ++mt) {
        const float* xr = &xs[(mt * 16 + lmod) * XSTR + lgrp * 8];
        #pragma unroll
        for (int kb = 0; kb < 8; ++kb) {
            float4 u = *(const float4*)(xr + kb * 32);
            float4 v = *(const float4*)(xr + kb * 32 + 4);
            half8v h;
            h[0] = (_Float16)u.x; h[1] = (_Float16)u.y;
            h[2] = (_Float16)u.z; h[3] = (_Float16)u.w;
            h[4] = (_Float16)v.x; h[5] = (_Float16)v.y;
            h[6] = (_Float16)v.z; h[7] = (_Float16)v.w;
            afrag[mt][kb] = h;
        }
    }

    float best[8], sec[8];
    int bestk[8];
    #pragma unroll
    for (int r = 0; r < 8; ++r) { best[r] = 3.4e38f; sec[r] = 3.4e38f; bestk[r] = 0; }

    for (int nt = 0; nt < 16; ++nt) {
        int n0 = wave * 256 + nt * 16;
        int n = n0 + lmod;
        f32x4 acc0 = {0.f, 0.f, 0.f, 0.f};
        f32x4 acc1 = {0.f, 0.f, 0.f, 0.f};
        #pragma unroll
        for (int kb = 0; kb < 8; ++kb) {
            half8v bfr = *(const half8v*)(cph + ((size_t)((kb << 2) + lgrp) * K_ + n) * 8);
            acc0 = __builtin_amdgcn_mfma_f32_16x16x32_f16(afrag[0][kb], bfr, acc0, 0, 0, 0);
            acc1 = __builtin_amdgcn_mfma_f32_16x16x32_f16(afrag[1][kb], bfr, acc1, 0, 0, 0);
        }
        float c2n = c2[n];
        #pragma unroll
        for (int i = 0; i < 4; ++i) {
            float s0 = c2n - 2.0f * acc0[i];      // row lgrp*4+i
            if (s0 < best[i]) { sec[i] = best[i]; best[i] = s0; bestk[i] = n; }
            else if (s0 < sec[i]) sec[i] = s0;
            float s1 = c2n - 2.0f * acc1[i];      // row 16+lgrp*4+i
            if (s1 < best[4 + i]) { sec[4 + i] = best[4 + i]; best[4 + i] = s1; bestk[4 + i] = n; }
            else if (s1 < sec[4 + i]) sec[4 + i] = s1;
        }
    }

    // cross-lane top-2 merge over the 16 lanes sharing lgrp (xor 1,2,4,8)
    #pragma unroll
    for (int r = 0; r < 8; ++r) {
        float v = best[r], s2 = sec[r];
        int ki = bestk[r];
        #pragma unroll
        for (int off = 1; off < 16; off <<= 1) {
            float ov = __shfl_xor(v, off, 64);
            int ok = __shfl_xor(ki, off, 64);
            float os = __shfl_xor(s2, off, 64);
            float nb = fminf(v, ov);
            float ns = fminf(fmaxf(v, ov), fminf(s2, os));
            if (ov < v || (ov == v && ok < ki)) ki = ok;
            v = nb; s2 = ns;
        }
        best[r] = v; sec[r] = s2; bestk[r] = ki;
    }
    if (lmod == 0) {
        #pragma unroll
        for (int i = 0; i < 4; ++i) {
            int rA = lgrp * 4 + i;
            wbest[wave][rA] = best[i];  wsec[wave][rA] = sec[i];  wk[wave][rA] = bestk[i];
            wbest[wave][16 + rA] = best[4 + i]; wsec[wave][16 + rA] = sec[4 + i]; wk[wave][16 + rA] = bestk[4 + i];
        }
    }
    __syncthreads();

    // cross-wave merge (waves in ascending code order -> strict < keeps min k)
    if (tid < 32) {
        float bv = wbest[0][tid], sv = wsec[0][tid];
        int bk = wk[0][tid];
        #pragma unroll
        for (int w = 1; w < 4; ++w) {
            float ob = wbest[w][tid], os = wsec[w][tid];
            int ok = wk[w][tid];
            if (ob < bv) { sv = fminf(bv, os); bv = ob; bk = ok; }
            else         { sv = fminf(sv, ob); }
        }
        int row = row0 + tid;
        if (sv - bv >= MARGIN_TAU) {
            codes[row] = bk;
            codes_f[row] = (float)bk;
        } else {
            int slot = atomicAdd(fb_count, 1);
            fb_rows[slot] = row;
        }
    }
}

// ---------------------------------------------------------------------------
// Kernel 4: fallback — np-f32 replication for flagged rows. One block per
// row (grid-stride). Thread handles codes k = tid + j*256; M = f32-rounded
// f64 dot; s = fl(fl(xx - fl(2M)) + cc); global first-index argmin.
// ---------------------------------------------------------------------------
__global__ __launch_bounds__(256) void fb_kernel(const float* __restrict__ x,
                                                 const float* __restrict__ ct,
                                                 const float* __restrict__ c2,
                                                 const int* __restrict__ fb_rows,
                                                 const int* __restrict__ fb_count,
                                                 int* __restrict__ codes,
                                                 float* __restrict__ codes_f) {
    __shared__ __align__(16) float xsr[256];
    __shared__ float wbv[4];
    __shared__ int wbk[4];
    int tid = threadIdx.x;
    int lane = tid & 63, wave = tid >> 6;
    int nfb = *fb_count;

    for (int idx = blockIdx.x; idx < nfb; idx += gridDim.x) {
        int row = fb_rows[idx];
        int b = row >> 11, t = row & 2047;
        __syncthreads();
        xsr[tid] = x[(size_t)b * (D_ * T_) + tid * T_ + t];
        __syncthreads();
        float xxv = pw256_sq(xsr, 1);   // np-pairwise |x|^2, bit-identical order

        double a0 = 0.0, a1 = 0.0, a2 = 0.0, a3 = 0.0;
        for (int d = 0; d < 256; ++d) {
            double xv = (double)xsr[d];
            const float* cp = ct + d * K_ + tid;
            a0 = fma(xv, (double)cp[0],   a0);
            a1 = fma(xv, (double)cp[256], a1);
            a2 = fma(xv, (double)cp[512], a2);
            a3 = fma(xv, (double)cp[768], a3);
        }
        float bv = 3.4e38f; int bk = 0;
        float s0 = __fadd_rn(__fsub_rn(xxv, __fmul_rn(2.0f, (float)a0)), c2[tid]);
        if (s0 < bv) { bv = s0; bk = tid; }
        float s1 = __fadd_rn(__fsub_rn(xxv, __fmul_rn(2.0f, (float)a1)), c2[tid + 256]);
        if (s1 < bv) { bv = s1; bk = tid + 256; }
        float s2 = __fadd_rn(__fsub_rn(xxv, __fmul_rn(2.0f, (float)a2)), c2[tid + 512]);
        if (s2 < bv) { bv = s2; bk = tid + 512; }
        float s3 = __fadd_rn(__fsub_rn(xxv, __fmul_rn(2.0f, (float)a3)), c2[tid + 768]);
        if (s3 < bv) { bv = s3; bk = tid + 768; }

        #pragma unroll
        for (int off = 1; off < 64; off <<= 1) {
            float ov = __shfl_xor(bv, off, 64);
            int ok = __shfl_xor(bk, off, 64);
            if (ov < bv || (ov == bv && ok < bk)) { bv = ov; bk = ok; }
        }
        if (lane == 0) { wbv[wave] = bv; wbk[wave] = bk; }
        __syncthreads();
        if (tid == 0) {
            float fbv = wbv[0]; int fbk = wbk[0];
            #pragma unroll
            for (int w = 1; w < 4; ++w) {
                if (wbv[w] < fbv || (wbv[w] == fbv && wbk[w] < fbk)) { fbv = wbv[w]; fbk = wbk[w]; }
            }
            codes[row] = fbk;
            codes_f[row] = (float)fbk;
        }
    }
}

// ---------------------------------------------------------------------------
// Kernel 5: music_sim — cosine similarity between projected x and context.
// ---------------------------------------------------------------------------
__global__ __launch_bounds__(256) void music_kernel(const float* __restrict__ x,
                                                    const float* __restrict__ mc,
                                                    const float* __restrict__ w,
                                                    const float* __restrict__ bp,
                                                    float* __restrict__ sim) {
    __shared__ float wsm[3 * 256];
    __shared__ float bs[3];
    int tid = threadIdx.x;
    for (int i = tid; i < 768; i += 256) wsm[i] = w[i];
    if (tid < 3) bs[tid] = bp[tid];
    __syncthreads();

    int row = blockIdx.x * 256 + tid;
    int b = row >> 11, t = row & 2047;
    const float* xp = x + (size_t)b * (D_ * T_) + t;
    float m0 = bs[0], m1 = bs[1], m2 = bs[2];
    #pragma unroll 8
    for (int d = 0; d < 256; ++d) {
        float xv = xp[d * T_];
        m0 = fmaf(wsm[d], xv, m0);
        m1 = fmaf(wsm[256 + d], xv, m1);
        m2 = fmaf(wsm[512 + d], xv, m2);
    }
    const float* mcp = mc + (size_t)b * (3 * T_) + t;
    float c0 = mcp[0], c1 = mcp[T_], c2v = mcp[2 * T_];
    float num = m0 * c0 + m1 * c1 + m2 * c2v;
    float npn = fmaxf(sqrtf(m0 * m0 + m1 * m1 + m2 * m2), EPS_COS);
    float ncn = fmaxf(sqrtf(c0 * c0 + c1 * c1 + c2v * c2v), EPS_COS);
    sim[row] = num / (npn * ncn);
}

// ---------------------------------------------------------------------------
// Kernel 6: histogram of codes
// ---------------------------------------------------------------------------
__global__ __launch_bounds__(256) void hist_kernel(const int* __restrict__ codes,
                                                   float* __restrict__ counts) {
    int row = blockIdx.x * 256 + threadIdx.x;
    if (row < BT_) atomicAdd(&counts[codes[row]], 1.0f);
}

// ---------------------------------------------------------------------------
// Kernel 7: quantized output + sum of (q-x)^2
// ---------------------------------------------------------------------------
__global__ __launch_bounds__(256) void quant_kernel(const float* __restrict__ x,
                                                    const float* __restrict__ cb,
                                                    const int* __restrict__ codes,
                                                    float* __restrict__ out0,
                                                    double* __restrict__ sums) {
    int n = blockIdx.x * 256 + threadIdx.x;
    int b = n >> 19;
    int rem = n & (524288 - 1);
    int d = rem >> 11;
    int t = rem & 2047;
    int code = codes[b * T_ + t];
    float q = cb[code * D_ + d];
    out0[n] = q;
    float diff = q - x[n];
    float sq = diff * diff;
    #pragma unroll
    for (int off = 32; off; off >>= 1) sq += __shfl_down(sq, off, 64);
    __shared__ float part[4];
    int lane = threadIdx.x & 63, wv = threadIdx.x >> 6;
    if (lane == 0) part[wv] = sq;
    __syncthreads();
    if (threadIdx.x == 0) {
        double s = (double)part[0] + part[1] + part[2] + part[3];
        atomicAdd(&sums[0], s);
    }
}

// ---------------------------------------------------------------------------
// Kernel 8: music loss sum
// ---------------------------------------------------------------------------
__global__ __launch_bounds__(256) void mloss_kernel(const float* __restrict__ sim,
                                                    const int* __restrict__ codes,
                                                    double* __restrict__ sums) {
    int idx = blockIdx.x * 256 + threadIdx.x;
    float val = 0.0f;
    if (idx < B_ * (T_ - 1)) {
        int b = idx / (T_ - 1);
        int t = idx - b * (T_ - 1);
        int base = b * T_ + t;
        if (codes[base + 1] != codes[base])
            val = fabsf(sim[base + 1] - sim[base]);
    }
    #pragma unroll
    for (int off = 32; off; off >>= 1) val += __shfl_down(val, off, 64);
    __shared__ float part[4];
    int lane = threadIdx.x & 63, wv = threadIdx.x >> 6;
    if (lane == 0) part[wv] = val;
    __syncthreads();
    if (threadIdx.x == 0) {
        double s = (double)part[0] + part[1] + part[2] + part[3];
        atomicAdd(&sums[1], s);
    }
}

// ---------------------------------------------------------------------------
// Kernel 9: finalize — perplexity + scalar outputs. Single block.
// ---------------------------------------------------------------------------
__global__ __launch_bounds__(256) void final_kernel(const float* __restrict__ counts,
                                                    const double* __restrict__ sums,
                                                    float* __restrict__ outS) {
    int tid = threadIdx.x;
    float e = 0.0f;
    for (int k = tid; k < K_; k += 256) {
        float p = counts[k] * (1.0f / (float)BT_);
        e += p * logf(p + 1e-10f);
    }
    #pragma unroll
    for (int off = 32; off; off >>= 1) e += __shfl_down(e, off, 64);
    __shared__ float part[4];
    int lane = tid & 63, wv = tid >> 6;
    if (lane == 0) part[wv] = e;
    __syncthreads();
    if (tid == 0) {
        float etot = part[0] + part[1] + part[2] + part[3];
        float perp = expf(-etot);
        float commitment = (float)(sums[0] / (double)BDT_);
        float ml = (float)(sums[1] / (double)(B_ * (T_ - 1)));
        outS[0] = commitment + MUSIC_W * ml;
        outS[1] = commitment;
        outS[2] = perp;
        outS[3] = ml;
    }
}

// ---------------------------------------------------------------------------
extern "C" void kernel_launch(void* const* d_in, const int* in_sizes, int n_in,
                              void* d_out, int out_size, void* d_ws, size_t ws_size,
                              hipStream_t stream) {
    const float* x   = (const float*)d_in[0];
    const float* mc  = (const float*)d_in[1];
    const float* cb  = (const float*)d_in[2];
    const float* wp  = (const float*)d_in[3];
    const float* bp  = (const float*)d_in[4];

    // workspace layout (float-offset units; sums first for 8B alignment)
    float* wsf = (float*)d_ws;
    double* sums     = (double*)wsf;               // 2 doubles  (4 floats)
    float* ct        = wsf + 4;                    // 262144
    float* c2        = ct + D_ * K_;               // 1024
    float* sim       = c2 + K_;                    // 32768
    float* counts    = sim + BT_;                  // 1024
    int*   codes     = (int*)(counts + K_);        // 32768
    int*   fb_rows   = codes + BT_;                // 32768
    int*   fb_count  = fb_rows + BT_;              // 1 (+3 pad)
    _Float16* cph    = (_Float16*)(fb_count + 4);  // 262144 halfs (16B aligned)

    float* out0    = (float*)d_out;                // quantized_st [16,256,2048]
    float* codes_f = out0 + BDT_;                  // codes [16,2048] as float
    float* outS    = codes_f + BT_;                // 4 scalars

    prep_trans<<<K_, 256, 0, stream>>>(cb, ct, cph, counts, sums, fb_count);
    prep_cc<<<4, 256, 0, stream>>>(cb, c2);
    argmin_kernel<<<BT_ / 32, 256, 0, stream>>>(x, cph, c2, codes, codes_f, fb_count, fb_rows);
    fb_kernel<<<1024, 256, 0, stream>>>(x, ct, c2, fb_rows, fb_count, codes, codes_f);
    music_kernel<<<BT_ / 256, 256, 0, stream>>>(x, mc, wp, bp, sim);
    hist_kernel<<<BT_ / 256, 256, 0, stream>>>(codes, counts);
    quant_kernel<<<BDT_ / 256, 256, 0, stream>>>(x, cb, codes, out0, sums);
    mloss_kernel<<<(B_ * (T_ - 1) + 255) / 256, 256, 0, stream>>>(sim, codes, sums);
    final_kernel<<<1, 256, 0, stream>>>(counts, sums, outS);
}